// Round 3
// baseline (278.511 us; speedup 1.0000x reference)
//
#include <hip/hip_runtime.h>
#include <hip/hip_bf16.h>

typedef __attribute__((ext_vector_type(4))) float f32x4;
typedef __attribute__((ext_vector_type(8))) short short8;
typedef __attribute__((ext_vector_type(4))) _Float16 f16x4;

#define NEG_BIG -9e15f

__device__ __forceinline__ short f2bf(float f) {
    unsigned u = __builtin_bit_cast(unsigned, f);
    u += 0x7fffu + ((u >> 16) & 1u);           // RNE to bf16
    return (short)(unsigned short)(u >> 16);
}

// Pre-kernel: W -> bf16 B-fragment layout (16x16x32 MFMA) + wa = W @ a (fp32 exact)
// frag layout: element ((kk*8+ct)*64 + lane)*8 + jj  =  bf16(W[kk*32 + (lane>>4)*8 + jj][ct*16 + (lane&15)])
__global__ void gat_pre(const float* __restrict__ W, const float* __restrict__ a_src,
                        const float* __restrict__ a_dst, unsigned short* __restrict__ wt,
                        float* __restrict__ wa) {
    int blk = blockIdx.x, t = threadIdx.x;
    if (blk < 8) {
        int e = blk * 256 + t;              // e = (kk*8+ct)*64 + lane
        int kk = e >> 9, ct = (e >> 6) & 7, lane = e & 63;
        int lq = lane >> 4, l15 = lane & 15;
        short8 v;
#pragma unroll
        for (int jj = 0; jj < 8; ++jj)
            v[jj] = f2bf(W[(kk * 32 + lq * 8 + jj) * 128 + ct * 16 + l15]);
        *(short8*)(wt + (size_t)e * 8) = v;
    } else if (t < 128) {
        float s1 = 0.f, s2 = 0.f;
        for (int o = 0; o < 128; ++o) {
            float w = W[t * 128 + o];
            s1 += w * a_src[o];
            s2 += w * a_dst[o];
        }
        wa[t] = s1; wa[128 + t] = s2;
    }
}

__device__ __forceinline__ void load_batch(const float* __restrict__ x,
                                           const int* __restrict__ adj,
                                           int b, int lq, int l15,
                                           float4 (&xv)[8], int (&av)[4]) {
    const float* xb = x + (size_t)b * 1920 + l15 * 128 + lq * 8;
#pragma unroll
    for (int kk = 0; kk < 4; ++kk) {
        if (l15 < 15) {
            xv[2 * kk]     = *(const float4*)(xb + kk * 32);
            xv[2 * kk + 1] = *(const float4*)(xb + kk * 32 + 4);
        } else {
            xv[2 * kk]     = make_float4(0.f, 0.f, 0.f, 0.f);
            xv[2 * kk + 1] = make_float4(0.f, 0.f, 0.f, 0.f);
        }
    }
    const int* ab = adj + (size_t)b * 225 + l15 * 15 + lq * 4;
#pragma unroll
    for (int r = 0; r < 4; ++r)
        av[r] = (l15 < 15 && lq * 4 + r < 15) ? ab[r] : 0;
}

// s-partials (exact fp32, lane's 32 columns) + bf16 A-fragment conversion
__device__ __forceinline__ void prep(const float4 (&xv)[8], const float* __restrict__ walds,
                                     int lq, float& ps, float& pd, short8 (&af)[4]) {
    ps = 0.f; pd = 0.f;
#pragma unroll
    for (int kk = 0; kk < 4; ++kk) {
        float4 a0 = xv[2 * kk], a1 = xv[2 * kk + 1];
        const float* wb = walds + kk * 32 + lq * 8;
        float4 s0 = *(const float4*)(wb);
        float4 s1 = *(const float4*)(wb + 4);
        float4 d0 = *(const float4*)(wb + 128);
        float4 d1 = *(const float4*)(wb + 132);
        ps += a0.x * s0.x + a0.y * s0.y + a0.z * s0.z + a0.w * s0.w
            + a1.x * s1.x + a1.y * s1.y + a1.z * s1.z + a1.w * s1.w;
        pd += a0.x * d0.x + a0.y * d0.y + a0.z * d0.z + a0.w * d0.w
            + a1.x * d1.x + a1.y * d1.y + a1.z * d1.z + a1.w * d1.w;
        short8 c;
        c[0] = f2bf(a0.x); c[1] = f2bf(a0.y); c[2] = f2bf(a0.z); c[3] = f2bf(a0.w);
        c[4] = f2bf(a1.x); c[5] = f2bf(a1.y); c[6] = f2bf(a1.z); c[7] = f2bf(a1.w);
        af[kk] = c;
    }
}

// walds layout: [0..127] = W@a_src, [128..255] = W@a_dst  (prep reads wb+128/wb+132)
__global__ __launch_bounds__(256, 4) void gat_main(
    const float* __restrict__ x, const int* __restrict__ adj,
    const unsigned short* __restrict__ wfrag, const float* __restrict__ wa,
    float* __restrict__ out, int B)
{
    __shared__ __align__(16) unsigned short wlds[16384];   // 32 KB W fragments
    __shared__ __align__(16) float walds[256];             // 1 KB wa

    const int t = threadIdx.x;
    const int lane = t & 63;
    const int lq = lane >> 4, l15 = lane & 15;

#pragma unroll
    for (int i = 0; i < 8; ++i)
        *(float4*)((char*)wlds + (t + 256 * i) * 16) =
            *(const float4*)((const char*)wfrag + (t + 256 * i) * 16);
    if (t < 64)
        *(float4*)(walds + t * 4) = *(const float4*)(wa + t * 4);
    __syncthreads();   // only barrier in the kernel; waves independent after this

    const int wid = blockIdx.x * 4 + (t >> 6);
    const int stride = gridDim.x * 4;

    float4 xr[8];
    int adjr[4];
    short8 af[4];
    float ps = 0.f, pd = 0.f;
    int adjc[4] = {0, 0, 0, 0};

    if (wid < B) {
        load_batch(x, adj, wid, lq, l15, xr, adjr);
        prep(xr, walds, lq, ps, pd, af);
#pragma unroll
        for (int r = 0; r < 4; ++r) adjc[r] = adjr[r];
    }

    for (int b = wid; b < B; b += stride) {
        const int bn = b + stride;
        const bool pn = bn < B;
        if (pn) load_batch(x, adj, bn, lq, l15, xr, adjr);   // prefetch next batch

        // reduce s over the 4 lq-lanes: every lane gets ss[i=l15], sd[i=l15]
        float ss = ps + __shfl_xor(ps, 16);
        ss += __shfl_xor(ss, 32);
        float sd = pd + __shfl_xor(pd, 16);
        sd += __shfl_xor(sd, 32);

        // h = x @ W : 32 MFMA, W B-fragments streamed from LDS
        f32x4 acc[8];
#pragma unroll
        for (int ct = 0; ct < 8; ++ct) acc[ct] = (f32x4){0.f, 0.f, 0.f, 0.f};
#pragma unroll
        for (int kk = 0; kk < 4; ++kk) {
#pragma unroll
            for (int ct = 0; ct < 8; ++ct) {
                short8 bf = *(const short8*)(wlds + ((size_t)(kk * 8 + ct) * 64 + lane) * 8);
                acc[ct] = __builtin_amdgcn_mfma_f32_16x16x32_bf16(af[kk], bf, acc[ct], 0, 0, 0);
            }
        }

        // softmax over i (axis=1): rows i = l15, this lane's columns j = lq*4+r
        float attv[4];
#pragma unroll
        for (int r = 0; r < 4; ++r) {
            float sdj = __shfl(sd, lq * 4 + r);
            float e = ss + sdj;
            e = e > 0.f ? e : 0.2f * e;             // leaky relu BEFORE mask (matches ref)
            e = adjc[r] > 0 ? e : NEG_BIG;
            if (l15 == 15) e = -INFINITY;           // pad row excluded exactly
            float m = e;
            m = fmaxf(m, __shfl_xor(m, 1));
            m = fmaxf(m, __shfl_xor(m, 2));
            m = fmaxf(m, __shfl_xor(m, 4));
            m = fmaxf(m, __shfl_xor(m, 8));
            float ev = __expf(e - m);
            float sm = ev;
            sm += __shfl_xor(sm, 1);
            sm += __shfl_xor(sm, 2);
            sm += __shfl_xor(sm, 4);
            sm += __shfl_xor(sm, 8);
            attv[r] = ev * __builtin_amdgcn_rcpf(sm);
        }

        // PV via 16x16x16 f16 MFMA: att is already A-frag (row=l15, k=lq*4+jj),
        // h acc (row=lq*4+r) is already B-frag (k=lq*4+jj) -> zero redistribution
        f16x4 ha;
        ha[0] = (_Float16)attv[0]; ha[1] = (_Float16)attv[1];
        ha[2] = (_Float16)attv[2]; ha[3] = (_Float16)attv[3];

        float* obase = out + (size_t)b * 1920;
        const f32x4 z4 = {0.f, 0.f, 0.f, 0.f};
        const int orow = lq * 4 + (lane & 3);       // row this lane stores after transpose
        const int ocol0 = (l15 & ~3);               // 4-aligned col base within ct block
#pragma unroll
        for (int ct = 0; ct < 8; ++ct) {
            f16x4 hb;
            hb[0] = (_Float16)acc[ct][0]; hb[1] = (_Float16)acc[ct][1];
            hb[2] = (_Float16)acc[ct][2]; hb[3] = (_Float16)acc[ct][3];
            f32x4 o4 = __builtin_amdgcn_mfma_f32_16x16x16f16(ha, hb, z4, 0, 0, 0);

            // elu (elementwise, before transpose)
            float v[4];
#pragma unroll
            for (int r = 0; r < 4; ++r) {
                float u = o4[r];
                v[r] = u > 0.f ? u : (__expf(u) - 1.f);
            }
            // 4x4 transpose across lanes (lane&3) x reg-index: 2 butterfly stages
#pragma unroll
            for (int k = 1; k <= 2; k <<= 1) {
                float tx[4];
#pragma unroll
                for (int j = 0; j < 4; ++j) tx[j] = __shfl_xor(v[j ^ k], k);
#pragma unroll
                for (int j = 0; j < 4; ++j)
                    if ((lane ^ j) & k) v[j] = tx[j];
            }
            // lane now holds row=orow, cols ct*16+ocol0 .. +3 -> dense 64B-sector stores
            if (orow < 15) {
                f32x4 w4 = {v[0], v[1], v[2], v[3]};
                __builtin_nontemporal_store(
                    w4, (f32x4*)(obase + orow * 128 + ct * 16 + ocol0));
            }
        }

        // fold prefetched batch into pipeline state (waitcnt lands here, ~full iter after issue)
        if (pn) {
            prep(xr, walds, lq, ps, pd, af);
#pragma unroll
            for (int r = 0; r < 4; ++r) adjc[r] = adjr[r];
        }
    }
}

extern "C" void kernel_launch(void* const* d_in, const int* in_sizes, int n_in,
                              void* d_out, int out_size, void* d_ws, size_t ws_size,
                              hipStream_t stream) {
    const float* x     = (const float*)d_in[0];
    const int*   adj   = (const int*)d_in[1];
    const float* W     = (const float*)d_in[2];
    const float* a_src = (const float*)d_in[3];
    const float* a_dst = (const float*)d_in[4];
    float* out = (float*)d_out;

    unsigned short* wt = (unsigned short*)d_ws;
    float* wa = (float*)((char*)d_ws + 32768);

    int B = in_sizes[0] / (15 * 128);

    gat_pre<<<9, 256, 0, stream>>>(W, a_src, a_dst, wt, wa);
    gat_main<<<1024, 256, 0, stream>>>(x, adj, wt, wa, out, B);
}

// Round 5
// 118.331 us; speedup vs baseline: 2.3537x; 2.3537x over previous
//
#include <hip/hip_runtime.h>
#include <hip/hip_bf16.h>

typedef __attribute__((ext_vector_type(4))) float f32x4;
typedef __attribute__((ext_vector_type(8))) short short8;
typedef __attribute__((ext_vector_type(4))) _Float16 f16x4;

#define NEG_BIG -9e15f

__device__ __forceinline__ short f2bf(float f) {
    unsigned u = __builtin_bit_cast(unsigned, f);
    u += 0x7fffu + ((u >> 16) & 1u);           // RNE to bf16
    return (short)(unsigned short)(u >> 16);
}

// Pre-kernel: W -> bf16 B-fragment layout (16x16x32 MFMA) + wa = W @ a (fp32 exact)
// frag layout: element ((kk*8+ct)*64 + lane)*8 + jj  =  bf16(W[kk*32 + (lane>>4)*8 + jj][ct*16 + (lane&15)])
__global__ void gat_pre(const float* __restrict__ W, const float* __restrict__ a_src,
                        const float* __restrict__ a_dst, unsigned short* __restrict__ wt,
                        float* __restrict__ wa) {
    int blk = blockIdx.x, t = threadIdx.x;
    if (blk < 8) {
        int e = blk * 256 + t;              // e = (kk*8+ct)*64 + lane
        int kk = e >> 9, ct = (e >> 6) & 7, lane = e & 63;
        int lq = lane >> 4, l15 = lane & 15;
        short8 v;
#pragma unroll
        for (int jj = 0; jj < 8; ++jj)
            v[jj] = f2bf(W[(kk * 32 + lq * 8 + jj) * 128 + ct * 16 + l15]);
        *(short8*)(wt + (size_t)e * 8) = v;
    } else if (t < 128) {
        float s1 = 0.f, s2 = 0.f;
        for (int o = 0; o < 128; ++o) {
            float w = W[t * 128 + o];
            s1 += w * a_src[o];
            s2 += w * a_dst[o];
        }
        wa[t] = s1; wa[128 + t] = s2;
    }
}

__device__ __forceinline__ void load_batch(const float* __restrict__ x,
                                           const int* __restrict__ adj,
                                           int b, int lq, int l15,
                                           float4 (&xv)[8], int (&av)[4]) {
    const float* xb = x + (size_t)b * 1920 + l15 * 128 + lq * 8;
#pragma unroll
    for (int kk = 0; kk < 4; ++kk) {
        if (l15 < 15) {
            xv[2 * kk]     = *(const float4*)(xb + kk * 32);
            xv[2 * kk + 1] = *(const float4*)(xb + kk * 32 + 4);
        } else {
            xv[2 * kk]     = make_float4(0.f, 0.f, 0.f, 0.f);
            xv[2 * kk + 1] = make_float4(0.f, 0.f, 0.f, 0.f);
        }
    }
    const int* ab = adj + (size_t)b * 225 + l15 * 15 + lq * 4;
#pragma unroll
    for (int r = 0; r < 4; ++r)
        av[r] = (l15 < 15 && lq * 4 + r < 15) ? ab[r] : 0;
}

// s-partials (exact fp32, lane's 32 columns) + bf16 A-fragment conversion
__device__ __forceinline__ void prep(const float4 (&xv)[8], const float* __restrict__ walds,
                                     int lq, float& ps, float& pd, short8 (&af)[4]) {
    ps = 0.f; pd = 0.f;
#pragma unroll
    for (int kk = 0; kk < 4; ++kk) {
        float4 a0 = xv[2 * kk], a1 = xv[2 * kk + 1];
        const float* wb = walds + kk * 32 + lq * 8;
        float4 s0 = *(const float4*)(wb);
        float4 s1 = *(const float4*)(wb + 4);
        float4 d0 = *(const float4*)(wb + 128);
        float4 d1 = *(const float4*)(wb + 132);
        ps += a0.x * s0.x + a0.y * s0.y + a0.z * s0.z + a0.w * s0.w
            + a1.x * s1.x + a1.y * s1.y + a1.z * s1.z + a1.w * s1.w;
        pd += a0.x * d0.x + a0.y * d0.y + a0.z * d0.z + a0.w * d0.w
            + a1.x * d1.x + a1.y * d1.y + a1.z * d1.z + a1.w * d1.w;
        short8 c;
        c[0] = f2bf(a0.x); c[1] = f2bf(a0.y); c[2] = f2bf(a0.z); c[3] = f2bf(a0.w);
        c[4] = f2bf(a1.x); c[5] = f2bf(a1.y); c[6] = f2bf(a1.z); c[7] = f2bf(a1.w);
        af[kk] = c;
    }
}

// walds layout: [0..127] = W@a_src, [128..255] = W@a_dst  (prep reads wb+128/wb+132)
__global__ __launch_bounds__(256, 3) void gat_main(
    const float* __restrict__ x, const int* __restrict__ adj,
    const unsigned short* __restrict__ wfrag, const float* __restrict__ wa,
    float* __restrict__ out, int B)
{
    __shared__ __align__(16) unsigned short wlds[16384];   // 32 KB W fragments
    __shared__ __align__(16) float walds[256];             // 1 KB wa
    __shared__ __align__(16) f32x4 stg[4][256];            // 16 KB: per-wave 4 KB store-staging

    const int t = threadIdx.x;
    const int wv = t >> 6;
    const int lane = t & 63;
    const int lq = lane >> 4, l15 = lane & 15;

#pragma unroll
    for (int i = 0; i < 8; ++i)
        *(float4*)((char*)wlds + (t + 256 * i) * 16) =
            *(const float4*)((const char*)wfrag + (t + 256 * i) * 16);
    if (t < 64)
        *(float4*)(walds + t * 4) = *(const float4*)(wa + t * 4);
    __syncthreads();   // only barrier in the kernel; waves independent after this

    const int wid = blockIdx.x * 4 + wv;
    const int stride = gridDim.x * 4;

    float4 xr[8];
    int adjr[4];
    short8 af[4];
    float ps = 0.f, pd = 0.f;
    int adjc[4] = {0, 0, 0, 0};

    if (wid < B) {
        load_batch(x, adj, wid, lq, l15, xr, adjr);
        prep(xr, walds, lq, ps, pd, af);
#pragma unroll
        for (int r = 0; r < 4; ++r) adjc[r] = adjr[r];
    }

    f32x4* const wbuf = &stg[wv][0];
    const int orow = lq * 4 + (lane & 3);     // row this lane owns after 4x4 transpose
    const int c4 = (l15 >> 2) & 3;            // quad-within-16-col block
    const int fsw = ((orow & 1) << 2) | (orow & 2);   // bank swizzle (2-way max)

    for (int b = wid; b < B; b += stride) {
        const int bn = b + stride;
        const bool pn = bn < B;
        if (pn) load_batch(x, adj, bn, lq, l15, xr, adjr);   // prefetch next batch

        // reduce s over the 4 lq-lanes: every lane gets ss[i=l15], sd[i=l15]
        float ss = ps + __shfl_xor(ps, 16);
        ss += __shfl_xor(ss, 32);
        float sd = pd + __shfl_xor(pd, 16);
        sd += __shfl_xor(sd, 32);

        // h = x @ W : 32 MFMA, W B-fragments streamed from LDS
        f32x4 acc[8];
#pragma unroll
        for (int ct = 0; ct < 8; ++ct) acc[ct] = (f32x4){0.f, 0.f, 0.f, 0.f};
#pragma unroll
        for (int kk = 0; kk < 4; ++kk) {
#pragma unroll
            for (int ct = 0; ct < 8; ++ct) {
                short8 bf = *(const short8*)(wlds + ((size_t)(kk * 8 + ct) * 64 + lane) * 8);
                acc[ct] = __builtin_amdgcn_mfma_f32_16x16x32_bf16(af[kk], bf, acc[ct], 0, 0, 0);
            }
        }

        // softmax over i (axis=1): rows i = l15, this lane's columns j = lq*4+r
        float attv[4];
#pragma unroll
        for (int r = 0; r < 4; ++r) {
            float sdj = __shfl(sd, lq * 4 + r);
            float e = ss + sdj;
            e = e > 0.f ? e : 0.2f * e;             // leaky relu BEFORE mask (matches ref)
            e = adjc[r] > 0 ? e : NEG_BIG;
            if (l15 == 15) e = -INFINITY;           // pad row excluded exactly
            float m = e;
            m = fmaxf(m, __shfl_xor(m, 1));
            m = fmaxf(m, __shfl_xor(m, 2));
            m = fmaxf(m, __shfl_xor(m, 4));
            m = fmaxf(m, __shfl_xor(m, 8));
            float ev = __expf(e - m);
            float sm = ev;
            sm += __shfl_xor(sm, 1);
            sm += __shfl_xor(sm, 2);
            sm += __shfl_xor(sm, 4);
            sm += __shfl_xor(sm, 8);
            attv[r] = ev * __builtin_amdgcn_rcpf(sm);
        }

        // PV via 16x16x16 f16 MFMA: att is already A-frag (row=l15, k=lq*4+jj),
        // h acc (row=lq*4+r) is already B-frag (k=lq*4+jj) -> zero redistribution
        f16x4 ha;
        ha[0] = (_Float16)attv[0]; ha[1] = (_Float16)attv[1];
        ha[2] = (_Float16)attv[2]; ha[3] = (_Float16)attv[3];

        const f32x4 z4 = {0.f, 0.f, 0.f, 0.f};
        f32x4 vq[8];     // transposed output: lane -> row orow, quad ct*4+c4
#pragma unroll
        for (int ct = 0; ct < 8; ++ct) {
            f16x4 hb;
            hb[0] = (_Float16)acc[ct][0]; hb[1] = (_Float16)acc[ct][1];
            hb[2] = (_Float16)acc[ct][2]; hb[3] = (_Float16)acc[ct][3];
            f32x4 o4 = __builtin_amdgcn_mfma_f32_16x16x16f16(ha, hb, z4, 0, 0, 0);

            // elu (elementwise, before transpose)
            float v[4];
#pragma unroll
            for (int r = 0; r < 4; ++r) {
                float u = o4[r];
                v[r] = u > 0.f ? u : (__expf(u) - 1.f);
            }
            // 4x4 transpose across lanes (lane&3) x reg-index: 2 butterfly stages
#pragma unroll
            for (int k = 1; k <= 2; k <<= 1) {
                float tx[4];
#pragma unroll
                for (int j = 0; j < 4; ++j) tx[j] = __shfl_xor(v[j ^ k], k);
#pragma unroll
                for (int j = 0; j < 4; ++j)
                    if ((lane ^ j) & k) v[j] = tx[j];
            }
            vq[ct] = (f32x4){v[0], v[1], v[2], v[3]};
        }

        // stage row-halves in LDS, emit flat full-line stores (1 KB / instruction).
        // NOTE: cross-lane LDS comms within the wave — the HW LDS pipe is in-order
        // per wave, but the COMPILER must be fenced or it reorders ds_read above
        // ds_write (per-thread slots are provably disjoint -> no dep). R4 bug.
        float* const obase = out + (size_t)b * 1920;
#pragma unroll
        for (int p = 0; p < 2; ++p) {
            if ((orow >> 3) == p) {
#pragma unroll
                for (int ct = 0; ct < 8; ++ct) {
                    int qs = (ct * 4 + c4) ^ fsw;
                    wbuf[(orow & 7) * 32 + qs] = vq[ct];
                }
            }
            // write->read fence: order + drain (cheap: writes land in ~30 cy)
            asm volatile("s_waitcnt lgkmcnt(0)" ::: "memory");
#pragma unroll
            for (int it = 0; it < 4; ++it) {
                int Q = p * 256 + it * 64 + lane;   // flat float4 index, 2 rows / instr
                if (Q < 480) {
                    int orr = Q >> 5;
                    int qs = (Q & 31) ^ (((orr & 1) << 2) | (orr & 2));
                    f32x4 val = wbuf[(orr & 7) * 32 + qs];
                    *(f32x4*)(obase + (size_t)Q * 4) = val;
                }
            }
            // read->next-write fence (WAR): keep next half's ds_writes below these reads
            asm volatile("" ::: "memory");
        }

        // fold prefetched batch into pipeline state (waitcnt lands here, ~full iter after issue)
        if (pn) {
            prep(xr, walds, lq, ps, pd, af);
#pragma unroll
            for (int r = 0; r < 4; ++r) adjc[r] = adjr[r];
        }
    }
}

extern "C" void kernel_launch(void* const* d_in, const int* in_sizes, int n_in,
                              void* d_out, int out_size, void* d_ws, size_t ws_size,
                              hipStream_t stream) {
    const float* x     = (const float*)d_in[0];
    const int*   adj   = (const int*)d_in[1];
    const float* W     = (const float*)d_in[2];
    const float* a_src = (const float*)d_in[3];
    const float* a_dst = (const float*)d_in[4];
    float* out = (float*)d_out;

    unsigned short* wt = (unsigned short*)d_ws;
    float* wa = (float*)((char*)d_ws + 32768);

    int B = in_sizes[0] / (15 * 128);

    gat_pre<<<9, 256, 0, stream>>>(W, a_src, a_dst, wt, wa);
    gat_main<<<768, 256, 0, stream>>>(x, adj, wt, wa, out, B);
}